// Round 2
// baseline (305.433 us; speedup 1.0000x reference)
//
#include <hip/hip_runtime.h>

#define NUM_EMB 512
#define DIM 64
#define HW 4096          // 64*64 spatial
#define NPOS 131072      // 32 * 4096
#define XELEMS 8388608   // 32*64*4096 — one output copy

// ---------------------------------------------------------------------------
// Kernel 1: per-codebook-row squared norms -> d_ws (512 floats)
// ---------------------------------------------------------------------------
__global__ void vq_esq_kernel(const float* __restrict__ e, float* __restrict__ esq) {
    int k = blockIdx.x * blockDim.x + threadIdx.x;
    if (k < NUM_EMB) {
        const float4* er = reinterpret_cast<const float4*>(e + k * DIM);
        float s = 0.f;
#pragma unroll
        for (int i = 0; i < DIM / 4; ++i) {
            float4 v = er[i];
            s += v.x * v.x + v.y * v.y + v.z * v.z + v.w * v.w;
        }
        esq[k] = s;
    }
}

// ---------------------------------------------------------------------------
// Kernel 2: main VQ — one thread per spatial position.
// x layout [B, D, H, W]: component d of position (b,hw) at b*D*HW + d*HW + hw.
// Consecutive threads take consecutive hw -> all x loads/stores coalesced.
// Embedding rows are wave-uniform -> expect scalar loads (s_load_dwordx16)
// feeding v_fmac_f32 with an SGPR operand (GEMV idiom; no LDS needed).
// ---------------------------------------------------------------------------
__global__ __launch_bounds__(256) void vq_main_kernel(const float* __restrict__ x,
                                                      const float* __restrict__ e,
                                                      const float* __restrict__ esq,
                                                      float* __restrict__ out) {
    int n = blockIdx.x * 256 + threadIdx.x;  // position id
    int b = n >> 12;                         // / 4096
    int hw = n & 4095;

    const float* xb = x + (size_t)b * (DIM * HW) + hw;

    float xr[DIM];
    float xsq = 0.f;
#pragma unroll
    for (int d = 0; d < DIM; ++d) {
        xr[d] = xb[(size_t)d * HW];
        xsq = fmaf(xr[d], xr[d], xsq);
    }

    float best = 3.4e38f;
    int bestk = 0;

    for (int k = 0; k < NUM_EMB; ++k) {
        const float* ek = e + k * DIM;
        float d0 = 0.f, d1 = 0.f, d2 = 0.f, d3 = 0.f;
#pragma unroll
        for (int d = 0; d < DIM; d += 4) {
            d0 = fmaf(xr[d + 0], ek[d + 0], d0);
            d1 = fmaf(xr[d + 1], ek[d + 1], d1);
            d2 = fmaf(xr[d + 2], ek[d + 2], d2);
            d3 = fmaf(xr[d + 3], ek[d + 3], d3);
        }
        float dot = (d0 + d1) + (d2 + d3);
        // reference: (xsq - 2*dot) + esq ; fma(-2,dot,xsq) rounds identically
        // (2*dot is exact -> one rounding), then + esq.
        float dist = fmaf(-2.f, dot, xsq) + esq[k];
        if (dist < best) {  // strict '<' keeps first index on ties, like argmin
            best = dist;
            bestk = k;
        }
    }

    // Gather the winning codebook row and write both tuple outputs.
    const float4* eb = reinterpret_cast<const float4*>(e + bestk * DIM);
    float* o0 = out + (size_t)b * (DIM * HW) + hw;
    float* o1 = o0 + XELEMS;
#pragma unroll
    for (int i = 0; i < DIM / 4; ++i) {
        float4 v = eb[i];
        o0[(size_t)(4 * i + 0) * HW] = v.x;
        o0[(size_t)(4 * i + 1) * HW] = v.y;
        o0[(size_t)(4 * i + 2) * HW] = v.z;
        o0[(size_t)(4 * i + 3) * HW] = v.w;
        o1[(size_t)(4 * i + 0) * HW] = v.x;
        o1[(size_t)(4 * i + 1) * HW] = v.y;
        o1[(size_t)(4 * i + 2) * HW] = v.z;
        o1[(size_t)(4 * i + 3) * HW] = v.w;
    }
}

extern "C" void kernel_launch(void* const* d_in, const int* in_sizes, int n_in,
                              void* d_out, int out_size, void* d_ws, size_t ws_size,
                              hipStream_t stream) {
    const float* x = (const float*)d_in[0];
    const float* e = (const float*)d_in[1];
    float* out = (float*)d_out;
    float* esq = (float*)d_ws;  // 512 floats of scratch

    vq_esq_kernel<<<1, NUM_EMB, 0, stream>>>(e, esq);
    vq_main_kernel<<<NPOS / 256, 256, 0, stream>>>(x, e, esq, out);
}

// Round 3
// 304.487 us; speedup vs baseline: 1.0031x; 1.0031x over previous
//
#include <hip/hip_runtime.h>

#define NUM_EMB 512
#define DIM 64
#define HW 4096          // 64*64 spatial
#define NPOS 131072      // 32 * 4096
#define XELEMS 8388608   // 32*64*4096 — one output copy

// ---------------------------------------------------------------------------
// Kernel 1: per-codebook-row squared norms -> d_ws (512 floats)
// ---------------------------------------------------------------------------
__global__ void vq_esq_kernel(const float* __restrict__ e, float* __restrict__ esq) {
    int k = blockIdx.x * blockDim.x + threadIdx.x;
    if (k < NUM_EMB) {
        const float4* er = reinterpret_cast<const float4*>(e + k * DIM);
        float s = 0.f;
#pragma unroll
        for (int i = 0; i < DIM / 4; ++i) {
            float4 v = er[i];
            s += v.x * v.x + v.y * v.y + v.z * v.z + v.w * v.w;
        }
        esq[k] = s;
    }
}

// ---------------------------------------------------------------------------
// Kernel 2: main VQ — one thread per spatial position.
//
// __launch_bounds__(256, 2): min 2 waves/EU -> VGPR budget 256. Round-2
// counters showed VGPR_Count=56: the allocator spilled xr[64] chasing
// 8 waves/EU that the grid (2048 waves total = 2/SIMD) can never use ->
// inner loop became scratch-load-bound (VALUBusy 30%, 236us). With the
// budget relaxed, xr stays in VGPRs and the k-loop is pure v_fmac_f32
// against wave-uniform (SGPR) codebook rows.
// ---------------------------------------------------------------------------
__global__ __launch_bounds__(256, 2) void vq_main_kernel(const float* __restrict__ x,
                                                         const float* __restrict__ e,
                                                         const float* __restrict__ esq,
                                                         float* __restrict__ out) {
    int n = blockIdx.x * 256 + threadIdx.x;  // position id
    int b = n >> 12;                         // / 4096
    int hw = n & 4095;

    const float* xb = x + (size_t)b * (DIM * HW) + hw;

    float xr[DIM];
    float xsq = 0.f;
#pragma unroll
    for (int d = 0; d < DIM; ++d) {
        xr[d] = xb[(size_t)d * HW];
        xsq = fmaf(xr[d], xr[d], xsq);
    }

    float best = 3.4e38f;
    int bestk = 0;

    for (int k = 0; k < NUM_EMB; ++k) {
        const float* ek = e + k * DIM;
        float d0 = 0.f, d1 = 0.f, d2 = 0.f, d3 = 0.f;
#pragma unroll
        for (int d = 0; d < DIM; d += 4) {
            d0 = fmaf(xr[d + 0], ek[d + 0], d0);
            d1 = fmaf(xr[d + 1], ek[d + 1], d1);
            d2 = fmaf(xr[d + 2], ek[d + 2], d2);
            d3 = fmaf(xr[d + 3], ek[d + 3], d3);
        }
        float dot = (d0 + d1) + (d2 + d3);
        // reference: (xsq - 2*dot) + esq ; fma(-2,dot,xsq) rounds identically
        // (2*dot is exact -> one rounding), then + esq. absmax==0 at round 2.
        float dist = fmaf(-2.f, dot, xsq) + esq[k];
        if (dist < best) {  // strict '<' keeps first index on ties, like argmin
            best = dist;
            bestk = k;
        }
    }

    // Gather the winning codebook row and write both tuple outputs.
    const float4* eb = reinterpret_cast<const float4*>(e + bestk * DIM);
    float* o0 = out + (size_t)b * (DIM * HW) + hw;
    float* o1 = o0 + XELEMS;
#pragma unroll
    for (int i = 0; i < DIM / 4; ++i) {
        float4 v = eb[i];
        o0[(size_t)(4 * i + 0) * HW] = v.x;
        o0[(size_t)(4 * i + 1) * HW] = v.y;
        o0[(size_t)(4 * i + 2) * HW] = v.z;
        o0[(size_t)(4 * i + 3) * HW] = v.w;
        o1[(size_t)(4 * i + 0) * HW] = v.x;
        o1[(size_t)(4 * i + 1) * HW] = v.y;
        o1[(size_t)(4 * i + 2) * HW] = v.z;
        o1[(size_t)(4 * i + 3) * HW] = v.w;
    }
}

extern "C" void kernel_launch(void* const* d_in, const int* in_sizes, int n_in,
                              void* d_out, int out_size, void* d_ws, size_t ws_size,
                              hipStream_t stream) {
    const float* x = (const float*)d_in[0];
    const float* e = (const float*)d_in[1];
    float* out = (float*)d_out;
    float* esq = (float*)d_ws;  // 512 floats of scratch

    vq_esq_kernel<<<1, NUM_EMB, 0, stream>>>(e, esq);
    vq_main_kernel<<<NPOS / 256, 256, 0, stream>>>(x, e, esq, out);
}

// Round 7
// 301.316 us; speedup vs baseline: 1.0137x; 1.0105x over previous
//
#include <hip/hip_runtime.h>

#define NUM_EMB 512
#define DIM 64
#define HW 4096          // 64*64 spatial
#define NPOS 131072      // 32 * 4096
#define XELEMS 8388608   // 32*64*4096 — one output copy

// ---------------------------------------------------------------------------
// Kernel 1: per-codebook-row squared norms -> d_ws (512 floats)
// ---------------------------------------------------------------------------
__global__ void vq_esq_kernel(const float* __restrict__ e, float* __restrict__ esq) {
    int k = blockIdx.x * blockDim.x + threadIdx.x;
    if (k < NUM_EMB) {
        const float4* er = reinterpret_cast<const float4*>(e + k * DIM);
        float s = 0.f;
#pragma unroll
        for (int i = 0; i < DIM / 4; ++i) {
            float4 v = er[i];
            s += v.x * v.x + v.y * v.y + v.z * v.z + v.w * v.w;
        }
        esq[k] = s;
    }
}

// ---------------------------------------------------------------------------
// Kernel 2: main VQ — one thread per spatial position.
//
// R2/R3 counters: VGPR_Count=56 — the compiler SANK the 64 x-loads into the
// k-loop (remat from memory) instead of keeping xr[64] live; VALUBusy 30%
// matches the resulting L1/L2-reload-bound loop. launch_bounds(256,2) alone
// did not change the decision (identical codegen).
//
// Fix: pin xr in VGPRs via empty asm ("+v") — the asm becomes the defining
// use, so reload-remat is illegal. amdgpu_waves_per_eu(2,2) grants the
// 256-VGPR budget (grid = 2048 waves = 2/SIMD anyway, so occupancy is
// unaffected). e-rows stay wave-uniform -> s_load_dwordx16 into SGPRs
// (SGPR=96 confirmed that path in R2).
// ---------------------------------------------------------------------------
__global__ __launch_bounds__(256)
__attribute__((amdgpu_waves_per_eu(2, 2)))
void vq_main_kernel(const float* __restrict__ x,
                    const float* __restrict__ e,
                    const float* __restrict__ esq,
                    float* __restrict__ out) {
    int n = blockIdx.x * 256 + threadIdx.x;  // position id
    int b = n >> 12;                         // / 4096
    int hw = n & 4095;

    const float* xb = x + (size_t)b * (DIM * HW) + hw;

    float xr[DIM];
#pragma unroll
    for (int d = 0; d < DIM; ++d) {
        xr[d] = xb[(size_t)d * HW];
    }
    // Pin every xr element into a VGPR: the asm is now its definition, so the
    // compiler cannot sink the global loads into the k-loop. All indices are
    // compile-time (fully unrolled) so the array itself stays in registers.
#pragma unroll
    for (int d = 0; d < DIM; d += 8) {
        asm volatile("" : "+v"(xr[d + 0]), "+v"(xr[d + 1]), "+v"(xr[d + 2]),
                          "+v"(xr[d + 3]), "+v"(xr[d + 4]), "+v"(xr[d + 5]),
                          "+v"(xr[d + 6]), "+v"(xr[d + 7]));
    }

    float xsq = 0.f;
#pragma unroll
    for (int d = 0; d < DIM; ++d) xsq = fmaf(xr[d], xr[d], xsq);

    float best = 3.4e38f;
    int bestk = 0;

    for (int k = 0; k < NUM_EMB; ++k) {
        const float* ek = e + k * DIM;
        float d0 = 0.f, d1 = 0.f, d2 = 0.f, d3 = 0.f;
#pragma unroll
        for (int d = 0; d < DIM; d += 4) {
            d0 = fmaf(xr[d + 0], ek[d + 0], d0);
            d1 = fmaf(xr[d + 1], ek[d + 1], d1);
            d2 = fmaf(xr[d + 2], ek[d + 2], d2);
            d3 = fmaf(xr[d + 3], ek[d + 3], d3);
        }
        float dot = (d0 + d1) + (d2 + d3);
        // reference: (xsq - 2*dot) + esq ; fma(-2,dot,xsq) rounds identically
        // (2*dot is exact -> one rounding), then + esq. absmax==0 at R2/R3.
        float dist = fmaf(-2.f, dot, xsq) + esq[k];
        if (dist < best) {  // strict '<' keeps first index on ties, like argmin
            best = dist;
            bestk = k;
        }
    }

    // Gather the winning codebook row and write both tuple outputs.
    const float4* eb = reinterpret_cast<const float4*>(e + bestk * DIM);
    float* o0 = out + (size_t)b * (DIM * HW) + hw;
    float* o1 = o0 + XELEMS;
#pragma unroll
    for (int i = 0; i < DIM / 4; ++i) {
        float4 v = eb[i];
        o0[(size_t)(4 * i + 0) * HW] = v.x;
        o0[(size_t)(4 * i + 1) * HW] = v.y;
        o0[(size_t)(4 * i + 2) * HW] = v.z;
        o0[(size_t)(4 * i + 3) * HW] = v.w;
        o1[(size_t)(4 * i + 0) * HW] = v.x;
        o1[(size_t)(4 * i + 1) * HW] = v.y;
        o1[(size_t)(4 * i + 2) * HW] = v.z;
        o1[(size_t)(4 * i + 3) * HW] = v.w;
    }
}

extern "C" void kernel_launch(void* const* d_in, const int* in_sizes, int n_in,
                              void* d_out, int out_size, void* d_ws, size_t ws_size,
                              hipStream_t stream) {
    const float* x = (const float*)d_in[0];
    const float* e = (const float*)d_in[1];
    float* out = (float*)d_out;
    float* esq = (float*)d_ws;  // 512 floats of scratch

    vq_esq_kernel<<<1, NUM_EMB, 0, stream>>>(e, esq);
    vq_main_kernel<<<NPOS / 256, 256, 0, stream>>>(x, e, esq, out);
}